// Round 13
// baseline (453.456 us; speedup 1.0000x reference)
//
#include <hip/hip_runtime.h>
#include <hip/hip_bf16.h>

#define E_EDGES   250000
#define D_NODE    128
#define D_EMB     200
#define D_STATIC  64
#define F_DIM     520
#define NT        33        // n-tiles of 16 (528 cols; tile 32 = cols 512..527, pack-zeroed past 519)
#define KT        17        // k-steps of 32 (544 k padded; cols 528..543 zero)
#define RS        552       // LDS row stride bf16. MUST stay 16B-aligned (R9/R10: 564 = 8 mod 16
                            // made odd-row ds_read_b128 misaligned -> 2x LDS time, -90%).
                            // 552 = 1104B, 276 dw mod 32 = 20, gcd 4 -> 2 lanes/bank = free (m136).
#define BM        96        // edges per block: 12 waves, 1 block/CU, 3 waves/SIMD ->
                            // 170 VGPR/wave budget = acc(72) + B ping-pong(24) + A(12) fits.
                            // (R12 lesson: 4 waves/SIMD forces single-buffered B -> K-loop
                            //  serializes MFMA against ~200cy L2 B-load waits.)
#define SMEM_BYTES (BM * RS * 2)   // 105984 B

typedef __attribute__((ext_vector_type(8))) short frag_t;   // 8 bf16 = 4 VGPR
typedef __attribute__((ext_vector_type(4))) float f32x4;

// Bit-twiddle RNE conversions (branchless VALU; exonerated by R10 factorial).
__device__ __forceinline__ unsigned short f2bf(float x) {
    union { float f; unsigned int u; } v; v.f = x;
    unsigned int r = v.u + 0x7FFFu + ((v.u >> 16) & 1u);   // RTNE
    return (unsigned short)(r >> 16);
}
__device__ __forceinline__ float bf2f(unsigned short u) {
    union { float f; unsigned int i; } v; v.i = ((unsigned int)u) << 16; return v.f;
}
__device__ __forceinline__ float elu(float z) {
    return (z > 0.0f) ? z : (__expf(z) - 1.0f);
}

// Pack W[k][n] (f32, row-major, ldw) into fragment-ordered bf16:
// Wp[((nt*KT + kt)*64 + lane)*8 + j] = W[kt*32 + (lane>>4)*8 + j][nt*16 + (lane&15)]
// zero outside (krows, ncols).
__global__ void pack_w_kernel(const float* __restrict__ W, unsigned short* __restrict__ Wp,
                              int ntiles, int krows, int ncols, int ldw) {
    int t = blockIdx.x * blockDim.x + threadIdx.x;
    if (t >= ntiles * KT * 64) return;
    int nt   = t / (KT * 64);
    int rem  = t % (KT * 64);
    int kt   = rem / 64;
    int lane = rem % 64;
    int n  = nt * 16 + (lane & 15);
    int kb = kt * 32 + (lane >> 4) * 8;
    unsigned short v[8];
    #pragma unroll
    for (int j = 0; j < 8; ++j) {
        int k = kb + j;
        float w = (k < krows && n < ncols) ? W[(long long)k * ldw + n] : 0.0f;
        v[j] = f2bf(w);
    }
    unsigned short* dst = Wp + (long long)t * 8;
    #pragma unroll
    for (int j = 0; j < 8; ++j) dst[j] = v[j];
}

// Zero-padded bias copy (544 floats) so the epilogue can read float4 unguarded
// even in tile 32 (cols 520..543 -> bias 0 keeps pad cols at exactly 0).
__global__ void pack_bias_kernel(const float* __restrict__ b, float* __restrict__ bp) {
    int i = blockIdx.x * blockDim.x + threadIdx.x;
    if (i < 544) bp[i] = (i < F_DIM) ? b[i] : 0.0f;
}

// One residual-MLP layer, in place on the 96x552 bf16 LDS panel.
// Wave owns CNT n-tiles (nt0..nt0+CNT-1) over all 96 rows: acc[CNT][6].
// mfma(Wfrag, hfrag): thread owns 4 consecutive cols of one row -> b64 epilogue.
// K-loop ROLLED (unrolled bodies spill, R4-R6) with depth-1 B ping-pong
// (single-buffer serializes MFMA vs L2 latency, R12).
template<int CNT>
__device__ __forceinline__ void layer_pass(char* __restrict__ h,
                                           const unsigned short* __restrict__ Wp,
                                           const float* __restrict__ biasp,
                                           int nt0, int lane) {
    const int idx = lane & 15;
    const int grp = lane >> 4;
    const char* wb = (const char*)Wp + (size_t)lane * 16;
    const char* abase = h + (size_t)idx * (RS * 2) + grp * 16;

    f32x4 acc[CNT][6];
    #pragma unroll
    for (int t = 0; t < CNT; ++t)
        #pragma unroll
        for (int m = 0; m < 6; ++m)
            acc[t][m] = (f32x4){0.f, 0.f, 0.f, 0.f};

    auto loadB = [&](frag_t* dst, int kt) {
        #pragma unroll
        for (int t = 0; t < CNT; ++t)
            dst[t] = *(const frag_t*)(wb + (size_t)((nt0 + t) * KT + kt) * 1024);
    };
    auto step = [&](const frag_t* b, int kt) {
        {   // chunk 0: m = 0..2 (live A = 12 regs)
            frag_t a[3];
            #pragma unroll
            for (int m = 0; m < 3; ++m)
                a[m] = *(const frag_t*)(abase + (size_t)(m * 16) * (RS * 2) + kt * 64);
            #pragma unroll
            for (int t = 0; t < CNT; ++t)
                #pragma unroll
                for (int m = 0; m < 3; ++m)
                    acc[t][m] = __builtin_amdgcn_mfma_f32_16x16x32_bf16(b[t], a[m], acc[t][m], 0, 0, 0);
        }
        {   // chunk 1: m = 3..5
            frag_t a[3];
            #pragma unroll
            for (int m = 0; m < 3; ++m)
                a[m] = *(const frag_t*)(abase + (size_t)((m + 3) * 16) * (RS * 2) + kt * 64);
            #pragma unroll
            for (int t = 0; t < CNT; ++t)
                #pragma unroll
                for (int m = 0; m < 3; ++m)
                    acc[t][m + 3] = __builtin_amdgcn_mfma_f32_16x16x32_bf16(b[t], a[m], acc[t][m + 3], 0, 0, 0);
        }
    };

    frag_t bA[CNT], bB[CNT];
    loadB(bA, 0);
    #pragma unroll 1
    for (int kp = 0; kp < 8; ++kp) {
        loadB(bB, 2 * kp + 1);
        step(bA, 2 * kp);
        loadB(bA, 2 * kp + 2);
        step(bB, 2 * kp + 1);
    }
    step(bA, 16);

    __syncthreads();   // all A-reads done -> safe to overwrite h in place

    // epilogue: h = elu(z + b) + h, b64 granularity (4 consecutive cols per thread)
    #pragma unroll
    for (int t = 0; t < CNT; ++t) {
        const int colb = (nt0 + t) * 16 + grp * 4;          // <= 524; biasp zero-padded
        const float4 bb = *(const float4*)(biasp + colb);
        #pragma unroll
        for (int m = 0; m < 6; ++m) {
            const int row = m * 16 + idx;
            char* p = h + (size_t)row * (RS * 2) + (size_t)colb * 2;
            ushort4 hv = *(const ushort4*)p;
            ushort4 o;
            o.x = f2bf(elu(acc[t][m][0] + bb.x) + bf2f(hv.x));
            o.y = f2bf(elu(acc[t][m][1] + bb.y) + bf2f(hv.y));
            o.z = f2bf(elu(acc[t][m][2] + bb.z) + bf2f(hv.z));
            o.w = f2bf(elu(acc[t][m][3] + bb.w) + bf2f(hv.w));
            *(ushort4*)p = o;
        }
    }
    __syncthreads();
}

__global__ __launch_bounds__(768, 3)
void edge_mlp_kernel(const float* __restrict__ X, const int* __restrict__ eidx,
                     const float* __restrict__ emb, const float* __restrict__ sef,
                     const float* __restrict__ bout,
                     const float* __restrict__ b1p, const float* __restrict__ b2p,
                     const unsigned short* __restrict__ W1p,
                     const unsigned short* __restrict__ W2p,
                     const unsigned short* __restrict__ Woutp,
                     float* __restrict__ out) {
    extern __shared__ char h[];          // 96 x 552 bf16, in-place panel
    const int tid  = threadIdx.x;
    const int wave = tid >> 6;           // 0..11
    const int lane = tid & 63;
    const long long base = (long long)blockIdx.x * BM;

    // ---- gather + f32->bf16 into h, wave w owns rows 8w..8w+7 ----
    // Lanes 0..15 fetch the wave's 16 indices (8 src + 8 dst); __shfl distributes.
    // Out-of-range edges CLAMPED (junk rows never stored -> harmless).
    // Outer loops rolled: 4 rows in flight caps VGPR pressure (R4-R6 spill lesson).
    int myidx = 0;
    if (lane < 16) {
        long long e = base + wave * 8 + (lane & 7);
        if (e >= E_EDGES) e = E_EDGES - 1;
        myidx = eidx[(long long)(lane >> 3) * E_EDGES + e];
    }

    #pragma unroll 1
    for (int g = 0; g < 2; ++g) {
        #pragma unroll
        for (int rr = 0; rr < 4; ++rr) {
            const int r = wave * 8 + g * 4 + rr;
            char* row = h + (size_t)r * (RS * 2);
            const int src = __shfl(myidx, g * 4 + rr);
            const int dst = __shfl(myidx, 8 + g * 4 + rr);
            float2 v = *(const float2*)(X + (long long)src * D_NODE + lane * 2);
            *(unsigned int*)(row + lane * 4) =
                (unsigned int)f2bf(v.x) | ((unsigned int)f2bf(v.y) << 16);
            float2 w = *(const float2*)(X + (long long)dst * D_NODE + lane * 2);
            *(unsigned int*)(row + 256 + lane * 4) =
                (unsigned int)f2bf(w.x) | ((unsigned int)f2bf(w.y) << 16);
        }
    }
    #pragma unroll 1
    for (int g = 0; g < 2; ++g) {
        #pragma unroll
        for (int rr = 0; rr < 4; ++rr) {
            if (lane < 50) {   // 200 emb floats per row
                long long e = base + wave * 8 + g * 4 + rr;
                if (e >= E_EDGES) e = E_EDGES - 1;
                char* row = h + (size_t)(wave * 8 + g * 4 + rr) * (RS * 2);
                float4 v = *(const float4*)(emb + e * D_EMB + (long long)lane * 4);
                unsigned int u0 = (unsigned int)f2bf(v.x) | ((unsigned int)f2bf(v.y) << 16);
                unsigned int u1 = (unsigned int)f2bf(v.z) | ((unsigned int)f2bf(v.w) << 16);
                *(uint2*)(row + 512 + lane * 8) = make_uint2(u0, u1);
            }
        }
    }
    #pragma unroll 1
    for (int q = 0; q < 2; ++q) {      // static: 4 rows per iteration (64 floats/row)
        const int r = wave * 8 + q * 4 + (lane >> 4);
        long long e = base + r;
        if (e >= E_EDGES) e = E_EDGES - 1;
        char* row = h + (size_t)r * (RS * 2);
        float4 v = *(const float4*)(sef + e * D_STATIC + (long long)(lane & 15) * 4);
        unsigned int u0 = (unsigned int)f2bf(v.x) | ((unsigned int)f2bf(v.y) << 16);
        unsigned int u1 = (unsigned int)f2bf(v.z) | ((unsigned int)f2bf(v.w) << 16);
        *(uint2*)(row + 912 + (lane & 15) * 8) = make_uint2(u0, u1);
        if ((lane & 15) < 6)          // zero pad cols 520..543 (48 B per row)
            *(uint2*)(row + 1040 + (lane & 15) * 8) = make_uint2(0u, 0u);
    }
    __syncthreads();

    // Column split: heavy waves 0..8 -> 3 tiles (0..26); light waves 9..11 -> 2
    // tiles (27..32, incl. tile 32 as a NORMAL tile: pack + padded bias make the
    // pad cols provably stay 0). Both branches execute 2 barriers per layer.
    if (wave < 9) {
        layer_pass<3>(h, W1p, b1p, wave * 3, lane);
        layer_pass<3>(h, W2p, b2p, wave * 3, lane);
    } else {
        layer_pass<2>(h, W1p, b1p, 27 + (wave - 9) * 2, lane);
        layer_pass<2>(h, W2p, b2p, 27 + (wave - 9) * 2, lane);
    }

    // ---- output projection: waves 0..5, wave w owns rows 16w..16w+15 ----
    if (wave < 6) {
        const int idx = lane & 15;
        const int grp = lane >> 4;
        f32x4 acc = (f32x4){0.f, 0.f, 0.f, 0.f};
        #pragma unroll 1
        for (int kt = 0; kt < KT; ++kt) {
            frag_t b = *(const frag_t*)((const char*)Woutp + (size_t)kt * 1024 + (size_t)lane * 16);
            frag_t a = *(const frag_t*)(h + (size_t)(wave * 16 + idx) * (RS * 2) + kt * 64 + grp * 16);
            acc = __builtin_amdgcn_mfma_f32_16x16x32_bf16(b, a, acc, 0, 0, 0);
        }
        if (grp < 2) {   // cols 0..7 real, grp>=2 are n-pad
            const long long e = base + wave * 16 + idx;
            if (e < E_EDGES) {
                float4 bb = *(const float4*)(bout + grp * 4);
                float4 o = make_float4(acc[0] + bb.x, acc[1] + bb.y,
                                       acc[2] + bb.z, acc[3] + bb.w);
                *(float4*)(out + e * 8 + grp * 4) = o;
            }
        }
    }
}

extern "C" void kernel_launch(void* const* d_in, const int* in_sizes, int n_in,
                              void* d_out, int out_size, void* d_ws, size_t ws_size,
                              hipStream_t stream) {
    const float* X    = (const float*)d_in[0];
    const int*   eidx = (const int*)d_in[1];
    const float* emb  = (const float*)d_in[2];
    const float* sef  = (const float*)d_in[3];
    const float* W1   = (const float*)d_in[4];
    const float* b1   = (const float*)d_in[5];
    const float* W2   = (const float*)d_in[6];
    const float* b2   = (const float*)d_in[7];
    const float* Wout = (const float*)d_in[8];
    const float* bout = (const float*)d_in[9];
    float* out = (float*)d_out;

    unsigned short* W1p   = (unsigned short*)d_ws;                 // 33*17*512 bf16
    unsigned short* W2p   = W1p + (size_t)NT * KT * 512;
    unsigned short* Woutp = W2p + (size_t)NT * KT * 512;           // 17*512 bf16
    float* b1p = (float*)(Woutp + (size_t)KT * 512);               // 544 f32 each
    float* b2p = b1p + 544;

    int total = NT * KT * 64;
    pack_w_kernel<<<(total + 255) / 256, 256, 0, stream>>>(W1, W1p, NT, F_DIM, F_DIM, F_DIM);
    pack_w_kernel<<<(total + 255) / 256, 256, 0, stream>>>(W2, W2p, NT, F_DIM, F_DIM, F_DIM);
    pack_w_kernel<<<(KT * 64 + 255) / 256, 256, 0, stream>>>(Wout, Woutp, 1, F_DIM, 8, 8);
    pack_bias_kernel<<<3, 256, 0, stream>>>(b1, b1p);
    pack_bias_kernel<<<3, 256, 0, stream>>>(b2, b2p);

    (void)hipFuncSetAttribute((const void*)edge_mlp_kernel,
                              hipFuncAttributeMaxDynamicSharedMemorySize, SMEM_BYTES);
    int nblocks = (E_EDGES + BM - 1) / BM;
    edge_mlp_kernel<<<nblocks, 768, SMEM_BYTES, stream>>>(
        X, eidx, emb, sef, bout, b1p, b2p, W1p, W2p, Woutp, out);
}